// Round 4
// baseline (1196.539 us; speedup 1.0000x reference)
//
#include <hip/hip_runtime.h>
#include <math.h>

typedef _Float16 half_t;
typedef _Float16 half2_t __attribute__((ext_vector_type(2)));
typedef _Float16 half8_t __attribute__((ext_vector_type(8)));
typedef union { half8_t v8; half2_t h2[4]; } H8;

#define T_ 64
#define B_ 256
#define D_ 16
#define S_ 64
#define H_ 128
#define O_ 8
#define NSTEP 63
#define NT 1024

// ws layout (halves): Wf3 [1024][128] | Wf1 [128][64] | Wf2 [128][128], row-major fp16
#define W3_OFF 0
#define W1_OFF 131072
#define W2_OFF 139264
#define WS_HALVES 155648

// AE[j] = coefficients on k[0..j] producing the NEXT stage input (j<5) or B_SOL (j==5)
__device__ constexpr float AE[6][6] = {
  {0.161f, 0.f, 0.f, 0.f, 0.f, 0.f},
  {-0.008480655492356989f, 0.335480655492357f, 0.f, 0.f, 0.f, 0.f},
  {2.8971530571054935f, -6.359448489975075f, 4.3622954328695815f, 0.f, 0.f, 0.f},
  {5.325864828439257f, -11.748883564062828f, 7.4955393428898365f, -0.09249506636175525f, 0.f, 0.f},
  {5.86145544294642f, -12.92096931784711f, 8.159367898576159f, -0.071584973281401f, -0.028269050394068383f, 0.f},
  {0.09646076681806523f, 0.01f, 0.4798896504144996f, 1.379008574103742f, -3.290069515436081f, 2.324710524099774f}
};
__device__ constexpr float CCn[6] = {0.f, 0.161f, 0.327f, 0.9f, 0.9800255409045097f, 1.f};

__device__ __forceinline__ float softplus_f(float x) {
  return fmaxf(x, 0.f) + log1pf(__expf(-fabsf(x)));
}
__device__ __forceinline__ float tanh_f(float x) {
  float xc = fminf(fmaxf(x, -12.f), 12.f);
  float e = __expf(2.f * xc);
  return (e - 1.f) * __builtin_amdgcn_rcpf(e + 1.f);
}
__device__ __forceinline__ float fdot2_f(half2_t a, half2_t b, float c) {
#if __has_builtin(__builtin_amdgcn_fdot2)
  return __builtin_amdgcn_fdot2(a, b, c, false);
#else
  return c + (float)a[0] * (float)b[0] + (float)a[1] * (float)b[1];
#endif
}

// ---------------- prologue: fp32 -> fp16 weight conversion (row-major) ----------------
__global__ __launch_bounds__(256) void convert_kernel(
    const float* __restrict__ Wf1, const float* __restrict__ Wf2,
    const float* __restrict__ Wf3, half_t* __restrict__ wsh)
{
  int q = blockIdx.x * 256 + threadIdx.x;
  if (q < W1_OFF) wsh[q] = (half_t)Wf3[q];
  else if (q < W2_OFF) wsh[q] = (half_t)Wf1[q - W1_OFF];
  else if (q < WS_HALVES) wsh[q] = (half_t)Wf2[q - W2_OFF];
}

// ---------------- main kernel ----------------
__global__ __launch_bounds__(NT, 4) void cde_kernel_f16(
    const float* __restrict__ ts,
    const float* __restrict__ coeff_d,
    const float* __restrict__ coeff_c,
    const float* __restrict__ coeff_b,
    const float* __restrict__ coeff_a,
    const float* __restrict__ Wi1, const float* __restrict__ bi1,
    const float* __restrict__ Wi2, const float* __restrict__ bi2,
    const float* __restrict__ bf1, const float* __restrict__ bf2,
    const float* __restrict__ bf3,
    const float* __restrict__ Wr, const float* __restrict__ br,
    const half_t* __restrict__ wsh,
    float* __restrict__ out)
{
  __shared__ __align__(16) half_t syj_h[S_];
  __shared__ __align__(16) half_t sh1h[H_];
  __shared__ __align__(16) half_t sh2h[H_];
  __shared__ float syf[S_];
  __shared__ float sini[H_];
  __shared__ float sx0[D_];
  __shared__ float sWr[O_ * S_];   // 2 KB
  __shared__ float sbr[O_];

  const int tid = threadIdx.x;
  const int b = blockIdx.x;

  // GEMV3 mapping: 64 s-groups x 16 lanes. Lane owns K-half kh of rows
  // (si*16+m) and (si*16+m+8); after K-combine it keeps d = kh? m+8 : m.
  const int si  = tid >> 4;
  const int lam = tid & 15;
  const int kh  = lam & 1;
  const int m   = lam >> 1;
  const int dI  = kh ? (m + 8) : m;
  // h1/h2 mapping: output o8 = tid>>3 (128), K-eighth q8 = tid&7
  const int o8  = tid >> 3;
  const int q8  = tid & 7;

  const half_t* __restrict__ w3 = wsh + W3_OFF;
  const half_t* __restrict__ w1 = wsh + W1_OFF;
  const half_t* __restrict__ w2 = wsh + W2_OFF;

  // ---- persistent weights, stored as half2 (clean v_dot2 operands) ----
  half2_t w3A[32], w3B[32];          // 64 VGPRs
  {
    const int rA = si * D_ + m;
    const half8_t* pA = (const half8_t*)(w3 + (size_t)rA * H_ + kh * 64);
    const half8_t* pB = (const half8_t*)(w3 + (size_t)(rA + 8) * H_ + kh * 64);
    #pragma unroll
    for (int c = 0; c < 8; ++c) {
      H8 ua; ua.v8 = pA[c];
      H8 ub; ub.v8 = pB[c];
      #pragma unroll
      for (int p = 0; p < 4; ++p) { w3A[c * 4 + p] = ua.h2[p]; w3B[c * 4 + p] = ub.h2[p]; }
    }
  }
  half2_t w1r[4];
  {
    H8 u; u.v8 = *(const half8_t*)(w1 + o8 * S_ + q8 * 8);
    #pragma unroll
    for (int p = 0; p < 4; ++p) w1r[p] = u.h2[p];
  }
  half2_t w2r[8];
  {
    const half8_t* p2 = (const half8_t*)(w2 + o8 * H_ + q8 * 16);
    H8 u0; u0.v8 = p2[0];
    H8 u1; u1.v8 = p2[1];
    #pragma unroll
    for (int p = 0; p < 4; ++p) { w2r[p] = u0.h2[p]; w2r[4 + p] = u1.h2[p]; }
  }
  const float bf1r = bf1[o8];
  const float bf2r = bf2[o8];
  const float bf3r = bf3[si * D_ + dI];

  // ---- one-time staging ----
  if (tid < O_ * S_) sWr[tid] = Wr[tid];
  if (tid < O_) sbr[tid] = br[tid];
  if (tid < D_) sx0[tid] = coeff_a[((size_t)b * NSTEP) * D_ + tid];
  __syncthreads();

  // ---- y0 = softplus(x0 @ Wi1^T + bi1) @ Wi2^T + bi2 (fp32, once) ----
  if (tid < H_) {
    float acc = bi1[tid];
    #pragma unroll
    for (int d = 0; d < D_; ++d) acc += sx0[d] * Wi1[tid * D_ + d];
    sini[tid] = softplus_f(acc);
  }
  __syncthreads();
  if (tid < S_) {
    float acc = bi2[tid];
    for (int h = 0; h < H_; ++h) acc += sini[h] * Wi2[tid * H_ + h];
    syf[tid] = acc;
  }
  __syncthreads();

  float syr = 0.f;
  float kr[6] = {0.f, 0.f, 0.f, 0.f, 0.f, 0.f};
  if (lam == 0) { syr = syf[si]; syj_h[si] = (half_t)syr; }
  __syncthreads();

  // ---- time loop ----
  for (int t = 0; t < NSTEP; ++t) {
    const float hstep = ts[t + 1] - ts[t];
    const size_t cbase = ((size_t)b * NSTEP + t) * D_ + dI;
    const float cbv = coeff_b[cbase];
    const float ccv = coeff_c[cbase];
    const float cdv = coeff_d[cbase];

    // out[b,t,:] from current y — overlapped with stage-0 h1
    if (tid < 64) {
      const int oo = tid >> 3, sl = tid & 7;
      const float4* p = (const float4*)(sWr + oo * S_ + sl * 8);
      float4 u0 = p[0], u1 = p[1];
      float a = syf[sl * 8 + 0] * u0.x + syf[sl * 8 + 1] * u0.y +
                syf[sl * 8 + 2] * u0.z + syf[sl * 8 + 3] * u0.w +
                syf[sl * 8 + 4] * u1.x + syf[sl * 8 + 5] * u1.y +
                syf[sl * 8 + 6] * u1.z + syf[sl * 8 + 7] * u1.w;
      a += __shfl_down(a, 4, 8);
      a += __shfl_down(a, 2, 8);
      a += __shfl_down(a, 1, 8);
      if (sl == 0) out[((size_t)b * T_ + t) * O_ + oo] = a + sbr[oo];
    }

    #pragma unroll
    for (int j = 0; j < 6; ++j) {
      // ---- h1 = softplus(yj @ Wf1^T + bf1), split-K x8 ----
      {
        H8 a; a.v8 = *(const half8_t*)(syj_h + q8 * 8);
        float acc = 0.f;
        #pragma unroll
        for (int p = 0; p < 4; ++p) acc = fdot2_f(w1r[p], a.h2[p], acc);
        acc += __shfl_xor(acc, 1);
        acc += __shfl_xor(acc, 2);
        acc += __shfl_xor(acc, 4);
        if (q8 == 0) sh1h[o8] = (half_t)softplus_f(acc + bf1r);
      }
      __syncthreads();

      // ---- h2 = softplus(h1 @ Wf2^T + bf2), split-K x8 ----
      {
        const half8_t* ap = (const half8_t*)(sh1h + q8 * 16);
        H8 a0; a0.v8 = ap[0];
        H8 a1; a1.v8 = ap[1];
        float acc = 0.f;
        #pragma unroll
        for (int p = 0; p < 4; ++p) acc = fdot2_f(w2r[p], a0.h2[p], acc);
        #pragma unroll
        for (int p = 0; p < 4; ++p) acc = fdot2_f(w2r[4 + p], a1.h2[p], acc);
        acc += __shfl_xor(acc, 1);
        acc += __shfl_xor(acc, 2);
        acc += __shfl_xor(acc, 4);
        if (q8 == 0) sh2h[o8] = (half_t)softplus_f(acc + bf2r);
      }
      __syncthreads();

      // ---- GEMV3 ----
      {
        const half8_t* ap = (const half8_t*)(sh2h + kh * 64);
        float accA = 0.f, accB = 0.f;
        #pragma unroll
        for (int c = 0; c < 8; ++c) {
          H8 a; a.v8 = ap[c];
          #pragma unroll
          for (int p = 0; p < 4; ++p) {
            accA = fdot2_f(w3A[c * 4 + p], a.h2[p], accA);
            accB = fdot2_f(w3B[c * 4 + p], a.h2[p], accB);
          }
        }
        // K-combine with neighbor lane (other K-half of the same 2 rows)
        accA += __shfl_xor(accA, 1);
        accB += __shfl_xor(accB, 1);
        const float dot = kh ? accB : accA;   // lane now owns row d = dI
        const float frac = CCn[j] * hstep;
        const float dx = cbv + frac * (2.f * ccv + 3.f * frac * cdv);
        float part = tanh_f(dot + bf3r) * dx;
        part += __shfl_down(part, 8, 16);
        part += __shfl_down(part, 4, 16);
        part += __shfl_down(part, 2, 16);
        part += __shfl_down(part, 1, 16);
        if (lam == 0) {
          kr[j] = part;
          float sacc = 0.f;
          #pragma unroll
          for (int mm = 0; mm <= j; ++mm) sacc += AE[j][mm] * kr[mm];
          if (j < 5) {
            syj_h[si] = (half_t)(syr + hstep * sacc);
          } else {
            syr += hstep * sacc;
            syj_h[si] = (half_t)syr;
            syf[si] = syr;
          }
        }
      }
      __syncthreads();
    }
  }

  // final projection: out[b,63,:]
  if (tid < 64) {
    const int oo = tid >> 3, sl = tid & 7;
    const float4* p = (const float4*)(sWr + oo * S_ + sl * 8);
    float4 u0 = p[0], u1 = p[1];
    float a = syf[sl * 8 + 0] * u0.x + syf[sl * 8 + 1] * u0.y +
              syf[sl * 8 + 2] * u0.z + syf[sl * 8 + 3] * u0.w +
              syf[sl * 8 + 4] * u1.x + syf[sl * 8 + 5] * u1.y +
              syf[sl * 8 + 6] * u1.z + syf[sl * 8 + 7] * u1.w;
    a += __shfl_down(a, 4, 8);
    a += __shfl_down(a, 2, 8);
    a += __shfl_down(a, 1, 8);
    if (sl == 0) out[((size_t)b * T_ + (T_ - 1)) * O_ + oo] = a + sbr[oo];
  }
}

extern "C" void kernel_launch(void* const* d_in, const int* in_sizes, int n_in,
                              void* d_out, int out_size, void* d_ws, size_t ws_size,
                              hipStream_t stream) {
  const float* ts  = (const float*)d_in[0];
  const float* cd  = (const float*)d_in[1];
  const float* cc  = (const float*)d_in[2];
  const float* cb  = (const float*)d_in[3];
  const float* ca  = (const float*)d_in[4];
  const float* Wi1 = (const float*)d_in[5];
  const float* bi1 = (const float*)d_in[6];
  const float* Wi2 = (const float*)d_in[7];
  const float* bi2 = (const float*)d_in[8];
  const float* Wf1 = (const float*)d_in[9];
  const float* bf1 = (const float*)d_in[10];
  const float* Wf2 = (const float*)d_in[11];
  const float* bf2 = (const float*)d_in[12];
  const float* Wf3 = (const float*)d_in[13];
  const float* bf3 = (const float*)d_in[14];
  const float* Wr  = (const float*)d_in[15];
  const float* br  = (const float*)d_in[16];

  half_t* wsh = (half_t*)d_ws;
  hipLaunchKernelGGL(convert_kernel, dim3((WS_HALVES + 255) / 256), dim3(256), 0, stream,
                     Wf1, Wf2, Wf3, wsh);
  hipLaunchKernelGGL(cde_kernel_f16, dim3(B_), dim3(NT), 0, stream,
                     ts, cd, cc, cb, ca, Wi1, bi1, Wi2, bi2,
                     bf1, bf2, bf3, Wr, br, wsh, (float*)d_out);
}

// Round 5
// 614.930 us; speedup vs baseline: 1.9458x; 1.9458x over previous
//
#include <hip/hip_runtime.h>
#include <math.h>

typedef _Float16 half_t;
typedef _Float16 half2_t __attribute__((ext_vector_type(2)));
typedef _Float16 half8_t __attribute__((ext_vector_type(8)));
typedef union { half8_t v8; half2_t h2[4]; } H8;

#define T_ 64
#define B_ 256
#define D_ 16
#define S_ 64
#define H_ 128
#define O_ 8
#define NSTEP 63
#define NT 512

// ws layout (halves): Wf3 [1024][128] | Wf1 [128][64] | Wf2 [128][128], row-major fp16
#define W3_OFF 0
#define W1_OFF 131072
#define W2_OFF 139264
#define WS_HALVES 155648

// AE[j] = coefficients on k[0..j] producing the NEXT stage input (j<5) or B_SOL (j==5)
__device__ constexpr float AE[6][6] = {
  {0.161f, 0.f, 0.f, 0.f, 0.f, 0.f},
  {-0.008480655492356989f, 0.335480655492357f, 0.f, 0.f, 0.f, 0.f},
  {2.8971530571054935f, -6.359448489975075f, 4.3622954328695815f, 0.f, 0.f, 0.f},
  {5.325864828439257f, -11.748883564062828f, 7.4955393428898365f, -0.09249506636175525f, 0.f, 0.f},
  {5.86145544294642f, -12.92096931784711f, 8.159367898576159f, -0.071584973281401f, -0.028269050394068383f, 0.f},
  {0.09646076681806523f, 0.01f, 0.4798896504144996f, 1.379008574103742f, -3.290069515436081f, 2.324710524099774f}
};
__device__ constexpr float CCn[6] = {0.f, 0.161f, 0.327f, 0.9f, 0.9800255409045097f, 1.f};

__device__ __forceinline__ float softplus_f(float x) {
  return fmaxf(x, 0.f) + __logf(1.f + __expf(-fabsf(x)));
}
__device__ __forceinline__ float tanh_f(float x) {
  float xc = fminf(fmaxf(x, -12.f), 12.f);
  float e = __expf(2.f * xc);
  return (e - 1.f) * __builtin_amdgcn_rcpf(e + 1.f);
}
__device__ __forceinline__ float fdot2_f(half2_t a, half2_t b, float c) {
#if __has_builtin(__builtin_amdgcn_fdot2)
  return __builtin_amdgcn_fdot2(a, b, c, false);
#else
  return c + (float)a[0] * (float)b[0] + (float)a[1] * (float)b[1];
#endif
}

// ---------------- prologue: fp32 -> fp16 weight conversion (row-major) ----------------
__global__ __launch_bounds__(256) void convert_kernel(
    const float* __restrict__ Wf1, const float* __restrict__ Wf2,
    const float* __restrict__ Wf3, half_t* __restrict__ wsh)
{
  int q = blockIdx.x * 256 + threadIdx.x;
  if (q < W1_OFF) wsh[q] = (half_t)Wf3[q];
  else if (q < W2_OFF) wsh[q] = (half_t)Wf1[q - W1_OFF];
  else if (q < WS_HALVES) wsh[q] = (half_t)Wf2[q - W2_OFF];
}

// ---------------- main kernel ----------------
// Role split (8 waves):
//   waves 0-1 : h1 (o = w*64+lane, in-lane full-K) + RK state + y-update
//   waves 2-5 : h2 (o = (w-2)*32 + lane/2, K-half = lane&1, one shuffle)
//   wave  6   : out-projection (stage 0 only)
//   all waves : GEMV3 (2 Wf3 rows per lane, in-lane full-K, no shuffles)
// wAux registers are role-overlaid: Wf1 rows on waves 0-1, Wf2 half-rows on 2-5.
__global__ void __launch_bounds__(NT) __attribute__((amdgpu_waves_per_eu(2, 2)))
cde_kernel_f16(
    const float* __restrict__ ts,
    const float* __restrict__ coeff_d,
    const float* __restrict__ coeff_c,
    const float* __restrict__ coeff_b,
    const float* __restrict__ coeff_a,
    const float* __restrict__ Wi1, const float* __restrict__ bi1,
    const float* __restrict__ Wi2, const float* __restrict__ bi2,
    const float* __restrict__ bf1, const float* __restrict__ bf2,
    const float* __restrict__ bf3,
    const float* __restrict__ Wr, const float* __restrict__ br,
    const half_t* __restrict__ wsh,
    float* __restrict__ out)
{
  __shared__ __align__(16) half_t syjbuf[2][S_];   // per-wave stage-input copies
  __shared__ __align__(16) half_t sh1h[H_];
  __shared__ __align__(16) half_t sh2h[H_];
  __shared__ __align__(16) float spart[NT];        // GEMV3 partials
  __shared__ float syf[S_];                        // fp32 y_t for projection
  __shared__ float sWr[O_ * S_];
  __shared__ float sbr[O_];
  __shared__ float sx0[D_];
  __shared__ float sini[H_];

  const int tid = threadIdx.x;
  const int b = blockIdx.x;
  const int w = tid >> 6;
  const int lane = tid & 63;

  // ---- persistent registers ----
  // Wf3: rows 2*tid and 2*tid+1, full K=128 each -> 128 VGPRs
  half2_t w3A[64], w3B[64];
  {
    const half8_t* pA = (const half8_t*)(wsh + W3_OFF + (size_t)(2 * tid) * H_);
    const half8_t* pB = (const half8_t*)(wsh + W3_OFF + (size_t)(2 * tid + 1) * H_);
    #pragma unroll
    for (int c = 0; c < 16; ++c) {
      H8 ua; ua.v8 = pA[c];
      H8 ub; ub.v8 = pB[c];
      #pragma unroll
      for (int q = 0; q < 4; ++q) { w3A[c * 4 + q] = ua.h2[q]; w3B[c * 4 + q] = ub.h2[q]; }
    }
  }
  const float bf3A = bf3[2 * tid];
  const float bf3B = bf3[2 * tid + 1];

  // role-overlaid aux weights (32 VGPRs)
  half2_t wAux[32];
  float biasr = 0.f;
  if (w < 2) {
    const int o = w * 64 + lane;
    const half8_t* p = (const half8_t*)(wsh + W1_OFF + o * S_);
    #pragma unroll
    for (int c = 0; c < 8; ++c) {
      H8 u; u.v8 = p[c];
      #pragma unroll
      for (int q = 0; q < 4; ++q) wAux[c * 4 + q] = u.h2[q];
    }
    biasr = bf1[o];
  } else if (w < 6) {
    const int o = (w - 2) * 32 + (lane >> 1);
    const int kh = lane & 1;
    const half8_t* p = (const half8_t*)(wsh + W2_OFF + o * H_ + kh * 64);
    #pragma unroll
    for (int c = 0; c < 8; ++c) {
      H8 u; u.v8 = p[c];
      #pragma unroll
      for (int q = 0; q < 4; ++q) wAux[c * 4 + q] = u.h2[q];
    }
    biasr = bf2[o];
  }

  // ---- one-time staging + y0 ----
  if (tid < O_ * S_) sWr[tid] = Wr[tid];
  if (tid < O_) sbr[tid] = br[tid];
  if (tid < D_) sx0[tid] = coeff_a[(size_t)b * NSTEP * D_ + tid];
  __syncthreads();
  if (tid < H_) {
    float acc = bi1[tid];
    #pragma unroll
    for (int d = 0; d < D_; ++d) acc += sx0[d] * Wi1[tid * D_ + d];
    sini[tid] = softplus_f(acc);
  }
  __syncthreads();
  if (tid < S_) {
    float acc = bi2[tid];
    for (int h = 0; h < H_; ++h) acc += sini[h] * Wi2[tid * H_ + h];
    syf[tid] = acc;
  }
  __syncthreads();

  // RK state: replicated on waves 0 and 1, lane = s
  float yr = 0.f;
  float kr[6] = {0.f, 0.f, 0.f, 0.f, 0.f, 0.f};
  if (w < 2) {
    yr = syf[lane];
    syjbuf[w][lane] = (half_t)yr;   // consumed by same wave -> no barrier needed
  }

  // ---- time loop ----
  for (int t = 0; t < NSTEP; ++t) {
    const float hstep = ts[t + 1] - ts[t];
    const int d0 = 2 * (tid & 7);
    const size_t cidx = ((size_t)b * NSTEP + t) * D_ + d0;
    const float2 vb = *(const float2*)(coeff_b + cidx);
    const float2 vc = *(const float2*)(coeff_c + cidx);
    const float2 vd = *(const float2*)(coeff_d + cidx);

    #pragma unroll
    for (int j = 0; j < 6; ++j) {
      // ---- h1 (waves 0-1): in-lane full-K, no shuffles ----
      if (w < 2) {
        const half8_t* yp = (const half8_t*)syjbuf[w];
        float acc = 0.f;
        #pragma unroll
        for (int c = 0; c < 8; ++c) {
          H8 u; u.v8 = yp[c];
          #pragma unroll
          for (int q = 0; q < 4; ++q) acc = fdot2_f(wAux[c * 4 + q], u.h2[q], acc);
        }
        sh1h[w * 64 + lane] = (half_t)softplus_f(acc + biasr);
      }
      __syncthreads();   // B1

      // ---- h2 (waves 2-5): one shuffle; projection (wave 6, stage 0) ----
      if (w >= 2 && w < 6) {
        const int kh = lane & 1;
        const half8_t* hp = (const half8_t*)(sh1h + kh * 64);
        float acc = 0.f;
        #pragma unroll
        for (int c = 0; c < 8; ++c) {
          H8 u; u.v8 = hp[c];
          #pragma unroll
          for (int q = 0; q < 4; ++q) acc = fdot2_f(wAux[c * 4 + q], u.h2[q], acc);
        }
        acc += __shfl_xor(acc, 1);
        if (kh == 0) sh2h[(w - 2) * 32 + (lane >> 1)] = (half_t)softplus_f(acc + biasr);
      } else if (w == 6 && j == 0) {
        const int oo = lane >> 3, kc = lane & 7;
        float a = 0.f;
        #pragma unroll
        for (int i = 0; i < 8; ++i) a += syf[kc * 8 + i] * sWr[oo * S_ + kc * 8 + i];
        a += __shfl_down(a, 4, 8);
        a += __shfl_down(a, 2, 8);
        a += __shfl_down(a, 1, 8);
        if (kc == 0) out[((size_t)b * T_ + t) * O_ + oo] = a + sbr[oo];
      }
      __syncthreads();   // B2

      // ---- GEMV3 (all waves): 2 rows per lane, in-lane full-K, no shuffles ----
      {
        const half8_t* hp = (const half8_t*)sh2h;
        float accA = 0.f, accB = 0.f;
        #pragma unroll
        for (int c = 0; c < 16; ++c) {
          H8 u; u.v8 = hp[c];
          #pragma unroll
          for (int q = 0; q < 4; ++q) {
            accA = fdot2_f(w3A[c * 4 + q], u.h2[q], accA);
            accB = fdot2_f(w3B[c * 4 + q], u.h2[q], accB);
          }
        }
        const float frac = CCn[j] * hstep;
        const float dxA = vb.x + frac * (2.f * vc.x + 3.f * frac * vd.x);
        const float dxB = vb.y + frac * (2.f * vc.y + 3.f * frac * vd.y);
        spart[tid] = tanh_f(accA + bf3A) * dxA + tanh_f(accB + bf3B) * dxB;
      }
      __syncthreads();   // B3

      // ---- y-update (waves 0-1): reduce 8 partials, advance RK state ----
      if (w < 2) {
        const float4* sp = (const float4*)(spart + lane * 8);
        float4 p0 = sp[0], p1 = sp[1];
        float kj = ((p0.x + p0.y) + (p0.z + p0.w)) + ((p1.x + p1.y) + (p1.z + p1.w));
        kr[j] = kj;
        float sacc = AE[j][0] * kr[0];
        #pragma unroll
        for (int m = 1; m < 6; ++m) if (m <= j) sacc += AE[j][m] * kr[m];
        float yn = yr + hstep * sacc;
        if (j == 5) {
          yr = yn;
          if (w == 0) syf[lane] = yn;   // ordered before wave-6 read by next B1
        }
        syjbuf[w][lane] = (half_t)yn;   // same-wave consumer
      }
    }
  }

  __syncthreads();
  // final projection: out[b,63,:]
  if (w == 6) {
    const int oo = lane >> 3, kc = lane & 7;
    float a = 0.f;
    #pragma unroll
    for (int i = 0; i < 8; ++i) a += syf[kc * 8 + i] * sWr[oo * S_ + kc * 8 + i];
    a += __shfl_down(a, 4, 8);
    a += __shfl_down(a, 2, 8);
    a += __shfl_down(a, 1, 8);
    if (kc == 0) out[((size_t)b * T_ + (T_ - 1)) * O_ + oo] = a + sbr[oo];
  }
}

extern "C" void kernel_launch(void* const* d_in, const int* in_sizes, int n_in,
                              void* d_out, int out_size, void* d_ws, size_t ws_size,
                              hipStream_t stream) {
  const float* ts  = (const float*)d_in[0];
  const float* cd  = (const float*)d_in[1];
  const float* cc  = (const float*)d_in[2];
  const float* cb  = (const float*)d_in[3];
  const float* ca  = (const float*)d_in[4];
  const float* Wi1 = (const float*)d_in[5];
  const float* bi1 = (const float*)d_in[6];
  const float* Wi2 = (const float*)d_in[7];
  const float* bi2 = (const float*)d_in[8];
  const float* Wf1 = (const float*)d_in[9];
  const float* bf1 = (const float*)d_in[10];
  const float* Wf2 = (const float*)d_in[11];
  const float* bf2 = (const float*)d_in[12];
  const float* Wf3 = (const float*)d_in[13];
  const float* bf3 = (const float*)d_in[14];
  const float* Wr  = (const float*)d_in[15];
  const float* br  = (const float*)d_in[16];

  half_t* wsh = (half_t*)d_ws;
  hipLaunchKernelGGL(convert_kernel, dim3((WS_HALVES + 255) / 256), dim3(256), 0, stream,
                     Wf1, Wf2, Wf3, wsh);
  hipLaunchKernelGGL(cde_kernel_f16, dim3(B_), dim3(NT), 0, stream,
                     ts, cd, cc, cb, ca, Wi1, bi1, Wi2, bi2,
                     bf1, bf2, bf3, Wr, br, wsh, (float*)d_out);
}